// Round 6
// baseline (114.913 us; speedup 1.0000x reference)
//
#include <hip/hip_runtime.h>

// EGNN layer, B=4 N=512 H=128 M=128. Fused, m never materialized.
//   A: hWi = h @ Wm[:H], hWj = h @ Wm[H:2H]   (256 thr, 4 rows, 2-way k-split)
//   B: per (b, i-pair, j-half): k-quad per thread as 2 packed-f32 pairs.
//      TARGET: VGPR<=64 + LDS ~16KB -> 8 blocks/CU (32 waves) for latency hiding.
//      red aliased onto rbuf (dead after j-loop); diag folded into sm2 init.
//   C: combines JS partials; h_new = [h | sm] @ Wf + bf; assembles x_new
// mask is all-True for this problem; diagonal exclusion is structural
// (rbuf diag row = 0 zeroes the x-path; sm2 starts at -diag contribution).

typedef float f2 __attribute__((ext_vector_type(2)));

constexpr int Bc = 4, Nc = 512, Hc = 128, Mc = 128;
constexpr int TI = 2;        // i-rows per block in kernel B
constexpr int JS = 2;        // j-split factor (blocks per i-pair)
constexpr int ROWS_A = 4;    // rows per block in kernel A
constexpr int ROWS_C = 8;    // rows per block in kernel C

// ---------------- Kernel A: input projections ----------------
__global__ __launch_bounds__(256) void egnn_proj(
    const float* __restrict__ h, const float* __restrict__ Wm,
    float* __restrict__ hWi, float* __restrict__ hWj)
{
    __shared__ float hs[ROWS_A][Hc];
    __shared__ float pI[ROWS_A][Mc], pJ[ROWS_A][Mc];
    const int t = threadIdx.x;
    const int m = t & 127, ks = t >> 7;   // ks: which half of k
    const int row0 = blockIdx.x * ROWS_A;

    for (int idx = t; idx < ROWS_A * Hc; idx += 256)
        ((float*)hs)[idx] = h[(size_t)row0 * Hc + idx];
    __syncthreads();

    float accI[ROWS_A] = {}, accJ[ROWS_A] = {};
    const int kbeg = ks * 64;
#pragma unroll 4
    for (int k = kbeg; k < kbeg + 64; ++k) {
        const float wi = Wm[(size_t)k * Mc + m];
        const float wj = Wm[(size_t)(Hc + k) * Mc + m];
#pragma unroll
        for (int r = 0; r < ROWS_A; ++r) {
            accI[r] = fmaf(hs[r][k], wi, accI[r]);
            accJ[r] = fmaf(hs[r][k], wj, accJ[r]);
        }
    }
    if (ks) {
#pragma unroll
        for (int r = 0; r < ROWS_A; ++r) { pI[r][m] = accI[r]; pJ[r][m] = accJ[r]; }
    }
    __syncthreads();
    if (!ks) {
#pragma unroll
        for (int r = 0; r < ROWS_A; ++r) {
            hWi[(size_t)(row0 + r) * Mc + m] = accI[r] + pI[r][m];
            hWj[(size_t)(row0 + r) * Mc + m] = accJ[r] + pJ[r][m];
        }
    }
}

// ---------------- Kernel B: fused pairwise core (j-split partials) ----------------
__global__ __launch_bounds__(256, 8) void egnn_main(
    const float* __restrict__ x,
    const float* __restrict__ Wm, const float* __restrict__ bm,
    const float* __restrict__ Wp, const float* __restrict__ bp,
    const float* __restrict__ hWi, const float* __restrict__ hWj,
    float* __restrict__ smp, float* __restrict__ xp)
{
    const int t = threadIdx.x;
    const int kq = t & 31;        // k-quad index: k = kq*4 + kk
    const int jp = t >> 5;        // j parity 0..7 within this block's half
    const int lane = t & 63;
    const int wv = t >> 6;

    const int bid  = blockIdx.x;
    const int js   = bid & (JS - 1);
    const int rest = bid >> 1;
    const int b  = rest / (Nc / TI);
    const int ig = rest % (Nc / TI);
    const int i0 = ig * TI;

    __shared__ float4 rbuf[TI][Nc];       // 16 KB; diag row = 0; red aliased after loop
    __shared__ float  rs[TI][3];          // sum_j r (js==0 block only)
    __shared__ float  xred[4][TI][3];
    float (*red)[4][32][4] = (float(*)[4][32][4])rbuf;   // [TI][wv][kq<32][kk]

    // build rbuf straight from global x (x[b] = 6KB, L2/L3-hot)
    const float* xg = x + (size_t)b * Nc * 3;
    {
        float xi[TI][3];
#pragma unroll
        for (int ti = 0; ti < TI; ++ti)
#pragma unroll
            for (int c = 0; c < 3; ++c)
                xi[ti][c] = xg[(i0 + ti) * 3 + c];
        for (int n = t; n < Nc; n += 256) {
            const float x0 = xg[n * 3 + 0], x1 = xg[n * 3 + 1], x2 = xg[n * 3 + 2];
#pragma unroll
            for (int ti = 0; ti < TI; ++ti) {
                const float r0 = x0 - xi[ti][0];
                const float r1 = x1 - xi[ti][1];
                const float r2 = x2 - xi[ti][2];
                rbuf[ti][n] = make_float4(r0, r1, r2, r0*r0 + r1*r1 + r2*r2);
            }
        }
    }
    __syncthreads();

    // rs[ti][c] = sum_j r[j][c] -- only the js==0 block contributes bp*rs
    if (js == 0 && wv < TI) {
        float s0 = 0.f, s1 = 0.f, s2 = 0.f;
        for (int j = lane; j < Nc; j += 64) {
            const float4 q = rbuf[wv][j];
            s0 += q.x; s1 += q.y; s2 += q.z;
        }
#pragma unroll
        for (int off = 32; off; off >>= 1) {
            s0 += __shfl_down(s0, off);
            s1 += __shfl_down(s1, off);
            s2 += __shfl_down(s2, off);
        }
        if (lane == 0) { rs[wv][0] = s0; rs[wv][1] = s1; rs[wv][2] = s2; }
    }

    const size_t rowb = (size_t)b * Nc;
    const int k0 = kq * 4;
    const f2 z2 = {0.f, 0.f};

    const float4 bm4 = *(const float4*)(bm + k0);
    const float4 wd4 = *(const float4*)(Wm + (size_t)2 * Hc * Mc + k0);
    const f2 wd2[2] = { {wd4.x, wd4.y}, {wd4.z, wd4.w} };

    f2 cik2[TI][2];
#pragma unroll
    for (int ti = 0; ti < TI; ++ti) {
        const float4 c4 = *(const float4*)(hWj + (rowb + i0 + ti) * Mc + k0);
        cik2[ti][0] = f2{c4.x + bm4.x, c4.y + bm4.y};
        cik2[ti][1] = f2{c4.z + bm4.z, c4.w + bm4.w};
    }

    const float* __restrict__ hWk = hWi + rowb * Mc + k0;
    const int j0 = js * 8 + jp;   // thread's j set: j mod 16 == j0 (32 values)

    // sm2 initialized to MINUS the diagonal term (rbuf diag=0 keeps x-path clean)
    f2 sm2[TI][2] = { {z2, z2}, {z2, z2} };
#pragma unroll
    for (int ti = 0; ti < TI; ++ti) {
        const int i = i0 + ti;
        if ((i & 15) == j0) {
            const float4 hd4 = *(const float4*)(hWk + (size_t)i * Mc);
            const f2 hd2[2] = { {hd4.x, hd4.y}, {hd4.z, hd4.w} };
#pragma unroll
            for (int p = 0; p < 2; ++p)
                sm2[ti][p] = -__builtin_elementwise_max(cik2[ti][p] + hd2[p], z2);
        }
    }

    f2 af[TI][2][3] = {};                    // [ti][pair][c]

#pragma unroll 4
    for (int it = 0; it < Nc / 16; ++it) {
        const int j = j0 + it * 16;
        const float4 hw4 = *(const float4*)(hWk + (size_t)j * Mc);
        const float4 q0 = rbuf[0][j];
        const float4 q1 = rbuf[1][j];
        const f2 g2[2] = { {hw4.x, hw4.y}, {hw4.z, hw4.w} };
        {
            const f2 d2b = {q0.w, q0.w}, qxb = {q0.x, q0.x};
            const f2 qyb = {q0.y, q0.y}, qzb = {q0.z, q0.z};
#pragma unroll
            for (int p = 0; p < 2; ++p) {
                const f2 u = __builtin_elementwise_fma(d2b, wd2[p], cik2[0][p]) + g2[p];
                const f2 mv = __builtin_elementwise_max(u, z2);
                sm2[0][p] += mv;
                af[0][p][0] = __builtin_elementwise_fma(mv, qxb, af[0][p][0]);
                af[0][p][1] = __builtin_elementwise_fma(mv, qyb, af[0][p][1]);
                af[0][p][2] = __builtin_elementwise_fma(mv, qzb, af[0][p][2]);
            }
        }
        {
            const f2 d2b = {q1.w, q1.w}, qxb = {q1.x, q1.x};
            const f2 qyb = {q1.y, q1.y}, qzb = {q1.z, q1.z};
#pragma unroll
            for (int p = 0; p < 2; ++p) {
                const f2 u = __builtin_elementwise_fma(d2b, wd2[p], cik2[1][p]) + g2[p];
                const f2 mv = __builtin_elementwise_max(u, z2);
                sm2[1][p] += mv;
                af[1][p][0] = __builtin_elementwise_fma(mv, qxb, af[1][p][0]);
                af[1][p][1] = __builtin_elementwise_fma(mv, qyb, af[1][p][1]);
                af[1][p][2] = __builtin_elementwise_fma(mv, qzb, af[1][p][2]);
            }
        }
    }

    __syncthreads();   // rbuf reads done block-wide; safe to reuse as red

    // ---- sm reduction: combine lane^32 (jp pair) in-register, then LDS ----
#pragma unroll
    for (int ti = 0; ti < TI; ++ti)
#pragma unroll
        for (int p = 0; p < 2; ++p) {
            sm2[ti][p].x += __shfl_xor(sm2[ti][p].x, 32);
            sm2[ti][p].y += __shfl_xor(sm2[ti][p].y, 32);
        }
    if (lane < 32) {
#pragma unroll
        for (int ti = 0; ti < TI; ++ti) {
            *(f2*)&red[ti][wv][lane][0] = sm2[ti][0];
            *(f2*)&red[ti][wv][lane][2] = sm2[ti][1];
        }
    }
    __syncthreads();
    if (t < Mc) {
        const int kq2 = t >> 2, kk2 = t & 3;
#pragma unroll
        for (int ti = 0; ti < TI; ++ti) {
            const float s = red[ti][0][kq2][kk2] + red[ti][1][kq2][kk2]
                          + red[ti][2][kq2][kk2] + red[ti][3][kq2][kk2];
            smp[((rowb + i0 + ti) * JS + js) * Mc + t] = s;
        }
    }

    // ---- x partial reduction (Wp loaded only here) ----
    const float4* wpv = (const float4*)(Wp + (size_t)k0 * 3);
    const float4 w0 = wpv[0], w1 = wpv[1], w2 = wpv[2];
    const float wpf[12] = { w0.x, w0.y, w0.z, w0.w, w1.x, w1.y, w1.z, w1.w,
                            w2.x, w2.y, w2.z, w2.w };
    float v[TI][3];
#pragma unroll
    for (int ti = 0; ti < TI; ++ti)
#pragma unroll
        for (int c = 0; c < 3; ++c)
            v[ti][c] = af[ti][0][c].x * wpf[0 * 3 + c] + af[ti][0][c].y * wpf[1 * 3 + c]
                     + af[ti][1][c].x * wpf[2 * 3 + c] + af[ti][1][c].y * wpf[3 * 3 + c];
#pragma unroll
    for (int off = 32; off; off >>= 1)
#pragma unroll
        for (int ti = 0; ti < TI; ++ti)
#pragma unroll
            for (int c = 0; c < 3; ++c)
                v[ti][c] += __shfl_down(v[ti][c], off);
    if (lane == 0)
#pragma unroll
        for (int ti = 0; ti < TI; ++ti)
#pragma unroll
            for (int c = 0; c < 3; ++c)
                xred[wv][ti][c] = v[ti][c];
    __syncthreads();
    if (t == 0) {
#pragma unroll
        for (int ti = 0; ti < TI; ++ti)
#pragma unroll
            for (int c = 0; c < 3; ++c) {
                float s = xred[0][ti][c] + xred[1][ti][c]
                        + xred[2][ti][c] + xred[3][ti][c];
                if (js == 0) s += bp[c] * rs[ti][c];
                xp[((rowb + i0 + ti) * JS + js) * 4 + c] = s;
            }
    }
}

// ---------------- Kernel C: combine partials; h_new; x assembly ----------------
__global__ __launch_bounds__(256) void egnn_hout(
    const float* __restrict__ x, const float* __restrict__ h,
    const float* __restrict__ smp, const float* __restrict__ xp,
    const float* __restrict__ Wf, const float* __restrict__ bf,
    float* __restrict__ xout, float* __restrict__ hout)
{
    __shared__ float hs[ROWS_C][Hc], ss[ROWS_C][Mc];
    __shared__ float part[ROWS_C][Hc];
    const int t = threadIdx.x;
    const int o = t & 127, ks = t >> 7;   // ks0: h-part, ks1: sm-part
    const int row0 = blockIdx.x * ROWS_C;

    for (int idx = t; idx < ROWS_C * Hc; idx += 256) {
        const int r = idx >> 7, c = idx & 127;
        const size_t row = row0 + r;
        hs[r][c] = h[row * Hc + c];
        ss[r][c] = smp[(row * JS + 0) * Mc + c] + smp[(row * JS + 1) * Mc + c];
    }
    if (t < ROWS_C * 3) {
        const int r = t / 3, c = t % 3;
        const size_t row = row0 + r;
        xout[row * 3 + c] = x[row * 3 + c]
            + (xp[(row * JS + 0) * 4 + c] + xp[(row * JS + 1) * 4 + c])
              * (1.0f / (float)(Nc - 1));
    }
    __syncthreads();

    float acc[ROWS_C] = {};
    const float* src = ks ? &ss[0][0] : &hs[0][0];
    const float* Wb = Wf + (size_t)ks * Hc * Hc;
#pragma unroll 4
    for (int k = 0; k < Hc; ++k) {
        const float w = Wb[(size_t)k * Hc + o];
#pragma unroll
        for (int r = 0; r < ROWS_C; ++r)
            acc[r] = fmaf(src[r * Hc + k], w, acc[r]);
    }
    if (ks) {
#pragma unroll
        for (int r = 0; r < ROWS_C; ++r) part[r][o] = acc[r];
    }
    __syncthreads();
    if (!ks) {
        const float bo = bf[o];
#pragma unroll
        for (int r = 0; r < ROWS_C; ++r)
            hout[(size_t)(row0 + r) * Hc + o] = acc[r] + part[r][o] + bo;
    }
}

extern "C" void kernel_launch(void* const* d_in, const int* in_sizes, int n_in,
                              void* d_out, int out_size, void* d_ws, size_t ws_size,
                              hipStream_t stream)
{
    const float* x  = (const float*)d_in[0];
    const float* h  = (const float*)d_in[1];
    // d_in[2] = mask (all-True; handled structurally)
    const float* Wm = (const float*)d_in[3];
    const float* bm = (const float*)d_in[4];
    const float* Wp = (const float*)d_in[5];
    const float* bp = (const float*)d_in[6];
    const float* Wf = (const float*)d_in[7];
    const float* bf = (const float*)d_in[8];

    float* xout = (float*)d_out;                         // (B,N,3)
    float* hout = (float*)d_out + (size_t)Bc * Nc * 3;   // (B,N,H)

    float* hWi = (float*)d_ws;                            // 1 MB
    float* hWj = hWi + (size_t)Bc * Nc * Mc;              // 1 MB
    float* smp = hWj + (size_t)Bc * Nc * Mc;              // 2 MB (JS partials)
    float* xp  = smp + (size_t)Bc * Nc * JS * Mc;         // 64 KB

    egnn_proj<<<Bc * Nc / ROWS_A, 256, 0, stream>>>(h, Wm, hWi, hWj);
    egnn_main<<<Bc * (Nc / TI) * JS, 256, 0, stream>>>(x, Wm, bm, Wp, bp, hWi, hWj, smp, xp);
    egnn_hout<<<Bc * Nc / ROWS_C, 256, 0, stream>>>(x, h, smp, xp, Wf, bf, xout, hout);
}

// Round 7
// 48.739 us; speedup vs baseline: 2.3577x; 2.3577x over previous
//
#include <hip/hip_runtime.h>

// EGNN layer, B=4 N=512 H=128 M=128. Fused, m never materialized.
//   A: hWi = h @ Wm[:H], hWj = h @ Wm[H:2H]   (256 thr, 4 rows, 2-way k-split)
//   B: per (b, i-pair, j-half): k-quad per thread as 2 packed-f32 pairs.
//      LDS 16.9KB (red aliased onto rbuf), grid 2048 (8 blocks/CU available),
//      launch_bounds (256,4): cap 128, compiler lands ~64 naturally (R3 data)
//      -> residency set by ACTUAL vgpr (64 -> 8 waves/SIMD), not the cap.
//      R6 lesson: (256,8) forced VGPR=32 -> wholesale spill (FETCH 115MB, 107us).
//   C: combines JS partials; h_new = [h | sm] @ Wf + bf; assembles x_new
// mask is all-True for this problem; diagonal exclusion is structural
// (rbuf diag row = 0 zeroes the x-path; sm2 starts at -diag contribution).

typedef float f2 __attribute__((ext_vector_type(2)));

constexpr int Bc = 4, Nc = 512, Hc = 128, Mc = 128;
constexpr int TI = 2;        // i-rows per block in kernel B
constexpr int JS = 2;        // j-split factor (blocks per i-pair)
constexpr int ROWS_A = 4;    // rows per block in kernel A
constexpr int ROWS_C = 8;    // rows per block in kernel C

// ---------------- Kernel A: input projections ----------------
__global__ __launch_bounds__(256) void egnn_proj(
    const float* __restrict__ h, const float* __restrict__ Wm,
    float* __restrict__ hWi, float* __restrict__ hWj)
{
    __shared__ float hs[ROWS_A][Hc];
    __shared__ float pI[ROWS_A][Mc], pJ[ROWS_A][Mc];
    const int t = threadIdx.x;
    const int m = t & 127, ks = t >> 7;   // ks: which half of k
    const int row0 = blockIdx.x * ROWS_A;

    for (int idx = t; idx < ROWS_A * Hc; idx += 256)
        ((float*)hs)[idx] = h[(size_t)row0 * Hc + idx];
    __syncthreads();

    float accI[ROWS_A] = {}, accJ[ROWS_A] = {};
    const int kbeg = ks * 64;
#pragma unroll 4
    for (int k = kbeg; k < kbeg + 64; ++k) {
        const float wi = Wm[(size_t)k * Mc + m];
        const float wj = Wm[(size_t)(Hc + k) * Mc + m];
#pragma unroll
        for (int r = 0; r < ROWS_A; ++r) {
            accI[r] = fmaf(hs[r][k], wi, accI[r]);
            accJ[r] = fmaf(hs[r][k], wj, accJ[r]);
        }
    }
    if (ks) {
#pragma unroll
        for (int r = 0; r < ROWS_A; ++r) { pI[r][m] = accI[r]; pJ[r][m] = accJ[r]; }
    }
    __syncthreads();
    if (!ks) {
#pragma unroll
        for (int r = 0; r < ROWS_A; ++r) {
            hWi[(size_t)(row0 + r) * Mc + m] = accI[r] + pI[r][m];
            hWj[(size_t)(row0 + r) * Mc + m] = accJ[r] + pJ[r][m];
        }
    }
}

// ---------------- Kernel B: fused pairwise core (j-split partials) ----------------
__global__ __launch_bounds__(256, 4) void egnn_main(
    const float* __restrict__ x,
    const float* __restrict__ Wm, const float* __restrict__ bm,
    const float* __restrict__ Wp, const float* __restrict__ bp,
    const float* __restrict__ hWi, const float* __restrict__ hWj,
    float* __restrict__ smp, float* __restrict__ xp)
{
    const int t = threadIdx.x;
    const int kq = t & 31;        // k-quad index: k = kq*4 + kk
    const int jp = t >> 5;        // j parity 0..7 within this block's half
    const int lane = t & 63;
    const int wv = t >> 6;

    const int bid  = blockIdx.x;
    const int js   = bid & (JS - 1);
    const int rest = bid >> 1;
    const int b  = rest / (Nc / TI);
    const int ig = rest % (Nc / TI);
    const int i0 = ig * TI;

    __shared__ float4 rbuf[TI][Nc];       // 16 KB; diag row = 0; red aliased after loop
    __shared__ float  rs[TI][3];          // sum_j r (js==0 block only)
    __shared__ float  xred[4][TI][3];
    float (*red)[4][32][4] = (float(*)[4][32][4])rbuf;   // [TI][wv][kq<32][kk]

    // build rbuf straight from global x (x[b] = 6KB, L2/L3-hot)
    const float* xg = x + (size_t)b * Nc * 3;
    {
        float xi[TI][3];
#pragma unroll
        for (int ti = 0; ti < TI; ++ti)
#pragma unroll
            for (int c = 0; c < 3; ++c)
                xi[ti][c] = xg[(i0 + ti) * 3 + c];
        for (int n = t; n < Nc; n += 256) {
            const float x0 = xg[n * 3 + 0], x1 = xg[n * 3 + 1], x2 = xg[n * 3 + 2];
#pragma unroll
            for (int ti = 0; ti < TI; ++ti) {
                const float r0 = x0 - xi[ti][0];
                const float r1 = x1 - xi[ti][1];
                const float r2 = x2 - xi[ti][2];
                rbuf[ti][n] = make_float4(r0, r1, r2, r0*r0 + r1*r1 + r2*r2);
            }
        }
    }
    __syncthreads();

    // rs[ti][c] = sum_j r[j][c] -- only the js==0 block contributes bp*rs
    if (js == 0 && wv < TI) {
        float s0 = 0.f, s1 = 0.f, s2 = 0.f;
        for (int j = lane; j < Nc; j += 64) {
            const float4 q = rbuf[wv][j];
            s0 += q.x; s1 += q.y; s2 += q.z;
        }
#pragma unroll
        for (int off = 32; off; off >>= 1) {
            s0 += __shfl_down(s0, off);
            s1 += __shfl_down(s1, off);
            s2 += __shfl_down(s2, off);
        }
        if (lane == 0) { rs[wv][0] = s0; rs[wv][1] = s1; rs[wv][2] = s2; }
    }

    const size_t rowb = (size_t)b * Nc;
    const int k0 = kq * 4;
    const f2 z2 = {0.f, 0.f};

    const float4 bm4 = *(const float4*)(bm + k0);
    const float4 wd4 = *(const float4*)(Wm + (size_t)2 * Hc * Mc + k0);
    const f2 wd2[2] = { {wd4.x, wd4.y}, {wd4.z, wd4.w} };

    f2 cik2[TI][2];
#pragma unroll
    for (int ti = 0; ti < TI; ++ti) {
        const float4 c4 = *(const float4*)(hWj + (rowb + i0 + ti) * Mc + k0);
        cik2[ti][0] = f2{c4.x + bm4.x, c4.y + bm4.y};
        cik2[ti][1] = f2{c4.z + bm4.z, c4.w + bm4.w};
    }

    const float* __restrict__ hWk = hWi + rowb * Mc + k0;
    const int j0 = js * 8 + jp;   // thread's j set: j mod 16 == j0 (32 values)

    // sm2 initialized to MINUS the diagonal term (rbuf diag=0 keeps x-path clean)
    f2 sm2[TI][2] = { {z2, z2}, {z2, z2} };
#pragma unroll
    for (int ti = 0; ti < TI; ++ti) {
        const int i = i0 + ti;
        if ((i & 15) == j0) {
            const float4 hd4 = *(const float4*)(hWk + (size_t)i * Mc);
            const f2 hd2[2] = { {hd4.x, hd4.y}, {hd4.z, hd4.w} };
#pragma unroll
            for (int p = 0; p < 2; ++p)
                sm2[ti][p] = -__builtin_elementwise_max(cik2[ti][p] + hd2[p], z2);
        }
    }

    f2 af[TI][2][3] = {};                    // [ti][pair][c]

#pragma unroll 4
    for (int it = 0; it < Nc / 16; ++it) {
        const int j = j0 + it * 16;
        const float4 hw4 = *(const float4*)(hWk + (size_t)j * Mc);
        const float4 q0 = rbuf[0][j];
        const float4 q1 = rbuf[1][j];
        const f2 g2[2] = { {hw4.x, hw4.y}, {hw4.z, hw4.w} };
        {
            const f2 d2b = {q0.w, q0.w}, qxb = {q0.x, q0.x};
            const f2 qyb = {q0.y, q0.y}, qzb = {q0.z, q0.z};
#pragma unroll
            for (int p = 0; p < 2; ++p) {
                const f2 u = __builtin_elementwise_fma(d2b, wd2[p], cik2[0][p]) + g2[p];
                const f2 mv = __builtin_elementwise_max(u, z2);
                sm2[0][p] += mv;
                af[0][p][0] = __builtin_elementwise_fma(mv, qxb, af[0][p][0]);
                af[0][p][1] = __builtin_elementwise_fma(mv, qyb, af[0][p][1]);
                af[0][p][2] = __builtin_elementwise_fma(mv, qzb, af[0][p][2]);
            }
        }
        {
            const f2 d2b = {q1.w, q1.w}, qxb = {q1.x, q1.x};
            const f2 qyb = {q1.y, q1.y}, qzb = {q1.z, q1.z};
#pragma unroll
            for (int p = 0; p < 2; ++p) {
                const f2 u = __builtin_elementwise_fma(d2b, wd2[p], cik2[1][p]) + g2[p];
                const f2 mv = __builtin_elementwise_max(u, z2);
                sm2[1][p] += mv;
                af[1][p][0] = __builtin_elementwise_fma(mv, qxb, af[1][p][0]);
                af[1][p][1] = __builtin_elementwise_fma(mv, qyb, af[1][p][1]);
                af[1][p][2] = __builtin_elementwise_fma(mv, qzb, af[1][p][2]);
            }
        }
    }

    __syncthreads();   // rbuf reads done block-wide; safe to reuse as red

    // ---- sm reduction: combine lane^32 (jp pair) in-register, then LDS ----
#pragma unroll
    for (int ti = 0; ti < TI; ++ti)
#pragma unroll
        for (int p = 0; p < 2; ++p) {
            sm2[ti][p].x += __shfl_xor(sm2[ti][p].x, 32);
            sm2[ti][p].y += __shfl_xor(sm2[ti][p].y, 32);
        }
    if (lane < 32) {
#pragma unroll
        for (int ti = 0; ti < TI; ++ti) {
            *(f2*)&red[ti][wv][lane][0] = sm2[ti][0];
            *(f2*)&red[ti][wv][lane][2] = sm2[ti][1];
        }
    }
    __syncthreads();
    if (t < Mc) {
        const int kq2 = t >> 2, kk2 = t & 3;
#pragma unroll
        for (int ti = 0; ti < TI; ++ti) {
            const float s = red[ti][0][kq2][kk2] + red[ti][1][kq2][kk2]
                          + red[ti][2][kq2][kk2] + red[ti][3][kq2][kk2];
            smp[((rowb + i0 + ti) * JS + js) * Mc + t] = s;
        }
    }

    // ---- x partial reduction (Wp loaded only here) ----
    const float4* wpv = (const float4*)(Wp + (size_t)k0 * 3);
    const float4 w0 = wpv[0], w1 = wpv[1], w2 = wpv[2];
    const float wpf[12] = { w0.x, w0.y, w0.z, w0.w, w1.x, w1.y, w1.z, w1.w,
                            w2.x, w2.y, w2.z, w2.w };
    float v[TI][3];
#pragma unroll
    for (int ti = 0; ti < TI; ++ti)
#pragma unroll
        for (int c = 0; c < 3; ++c)
            v[ti][c] = af[ti][0][c].x * wpf[0 * 3 + c] + af[ti][0][c].y * wpf[1 * 3 + c]
                     + af[ti][1][c].x * wpf[2 * 3 + c] + af[ti][1][c].y * wpf[3 * 3 + c];
#pragma unroll
    for (int off = 32; off; off >>= 1)
#pragma unroll
        for (int ti = 0; ti < TI; ++ti)
#pragma unroll
            for (int c = 0; c < 3; ++c)
                v[ti][c] += __shfl_down(v[ti][c], off);
    if (lane == 0)
#pragma unroll
        for (int ti = 0; ti < TI; ++ti)
#pragma unroll
            for (int c = 0; c < 3; ++c)
                xred[wv][ti][c] = v[ti][c];
    __syncthreads();
    if (t == 0) {
#pragma unroll
        for (int ti = 0; ti < TI; ++ti)
#pragma unroll
            for (int c = 0; c < 3; ++c) {
                float s = xred[0][ti][c] + xred[1][ti][c]
                        + xred[2][ti][c] + xred[3][ti][c];
                if (js == 0) s += bp[c] * rs[ti][c];
                xp[((rowb + i0 + ti) * JS + js) * 4 + c] = s;
            }
    }
}

// ---------------- Kernel C: combine partials; h_new; x assembly ----------------
__global__ __launch_bounds__(256) void egnn_hout(
    const float* __restrict__ x, const float* __restrict__ h,
    const float* __restrict__ smp, const float* __restrict__ xp,
    const float* __restrict__ Wf, const float* __restrict__ bf,
    float* __restrict__ xout, float* __restrict__ hout)
{
    __shared__ float hs[ROWS_C][Hc], ss[ROWS_C][Mc];
    __shared__ float part[ROWS_C][Hc];
    const int t = threadIdx.x;
    const int o = t & 127, ks = t >> 7;   // ks0: h-part, ks1: sm-part
    const int row0 = blockIdx.x * ROWS_C;

    for (int idx = t; idx < ROWS_C * Hc; idx += 256) {
        const int r = idx >> 7, c = idx & 127;
        const size_t row = row0 + r;
        hs[r][c] = h[row * Hc + c];
        ss[r][c] = smp[(row * JS + 0) * Mc + c] + smp[(row * JS + 1) * Mc + c];
    }
    if (t < ROWS_C * 3) {
        const int r = t / 3, c = t % 3;
        const size_t row = row0 + r;
        xout[row * 3 + c] = x[row * 3 + c]
            + (xp[(row * JS + 0) * 4 + c] + xp[(row * JS + 1) * 4 + c])
              * (1.0f / (float)(Nc - 1));
    }
    __syncthreads();

    float acc[ROWS_C] = {};
    const float* src = ks ? &ss[0][0] : &hs[0][0];
    const float* Wb = Wf + (size_t)ks * Hc * Hc;
#pragma unroll 4
    for (int k = 0; k < Hc; ++k) {
        const float w = Wb[(size_t)k * Hc + o];
#pragma unroll
        for (int r = 0; r < ROWS_C; ++r)
            acc[r] = fmaf(src[r * Hc + k], w, acc[r]);
    }
    if (ks) {
#pragma unroll
        for (int r = 0; r < ROWS_C; ++r) part[r][o] = acc[r];
    }
    __syncthreads();
    if (!ks) {
        const float bo = bf[o];
#pragma unroll
        for (int r = 0; r < ROWS_C; ++r)
            hout[(size_t)(row0 + r) * Hc + o] = acc[r] + part[r][o] + bo;
    }
}

extern "C" void kernel_launch(void* const* d_in, const int* in_sizes, int n_in,
                              void* d_out, int out_size, void* d_ws, size_t ws_size,
                              hipStream_t stream)
{
    const float* x  = (const float*)d_in[0];
    const float* h  = (const float*)d_in[1];
    // d_in[2] = mask (all-True; handled structurally)
    const float* Wm = (const float*)d_in[3];
    const float* bm = (const float*)d_in[4];
    const float* Wp = (const float*)d_in[5];
    const float* bp = (const float*)d_in[6];
    const float* Wf = (const float*)d_in[7];
    const float* bf = (const float*)d_in[8];

    float* xout = (float*)d_out;                         // (B,N,3)
    float* hout = (float*)d_out + (size_t)Bc * Nc * 3;   // (B,N,H)

    float* hWi = (float*)d_ws;                            // 1 MB
    float* hWj = hWi + (size_t)Bc * Nc * Mc;              // 1 MB
    float* smp = hWj + (size_t)Bc * Nc * Mc;              // 2 MB (JS partials)
    float* xp  = smp + (size_t)Bc * Nc * JS * Mc;         // 64 KB

    egnn_proj<<<Bc * Nc / ROWS_A, 256, 0, stream>>>(h, Wm, hWi, hWj);
    egnn_main<<<Bc * (Nc / TI) * JS, 256, 0, stream>>>(x, Wm, bm, Wp, bp, hWi, hWj, smp, xp);
    egnn_hout<<<Bc * Nc / ROWS_C, 256, 0, stream>>>(x, h, smp, xp, Wf, bf, xout, hout);
}

// Round 8
// 45.566 us; speedup vs baseline: 2.5219x; 1.0697x over previous
//
#include <hip/hip_runtime.h>

// EGNN layer, B=4 N=512 H=128 M=128. Fused, m never materialized.
//   A: hWi = h @ Wm[:H], hWj = h @ Wm[H:2H]   (256 thr, 4 rows, 2-way k-split)
//   B: per (b, i): ONE i-row per block (TI=1), k-quad per thread as 2 packed
//      f2 pairs, 8-way j-parity. Small state (~60 VGPR) + 10.3KB LDS + grid
//      2048 -> 7-8 blocks/CU resident. R7 lesson: TI=2 packed needed ~128 VGPR,
//      so residency was register-capped at 16 waves/CU no matter the grid.
//   C: h_new = [h | sm] @ Wf + bf
// mask is all-True for this problem; diagonal exclusion is structural
// (rbuf diag row = 0 zeroes the x-path; sm2 starts at -diag contribution).

typedef float f2 __attribute__((ext_vector_type(2)));

constexpr int Bc = 4, Nc = 512, Hc = 128, Mc = 128;
constexpr int ROWS_A = 4;    // rows per block in kernel A
constexpr int ROWS_C = 8;    // rows per block in kernel C

// ---------------- Kernel A: input projections ----------------
__global__ __launch_bounds__(256) void egnn_proj(
    const float* __restrict__ h, const float* __restrict__ Wm,
    float* __restrict__ hWi, float* __restrict__ hWj)
{
    __shared__ float hs[ROWS_A][Hc];
    __shared__ float pI[ROWS_A][Mc], pJ[ROWS_A][Mc];
    const int t = threadIdx.x;
    const int m = t & 127, ks = t >> 7;   // ks: which half of k
    const int row0 = blockIdx.x * ROWS_A;

    for (int idx = t; idx < ROWS_A * Hc; idx += 256)
        ((float*)hs)[idx] = h[(size_t)row0 * Hc + idx];
    __syncthreads();

    float accI[ROWS_A] = {}, accJ[ROWS_A] = {};
    const int kbeg = ks * 64;
#pragma unroll 4
    for (int k = kbeg; k < kbeg + 64; ++k) {
        const float wi = Wm[(size_t)k * Mc + m];
        const float wj = Wm[(size_t)(Hc + k) * Mc + m];
#pragma unroll
        for (int r = 0; r < ROWS_A; ++r) {
            accI[r] = fmaf(hs[r][k], wi, accI[r]);
            accJ[r] = fmaf(hs[r][k], wj, accJ[r]);
        }
    }
    if (ks) {
#pragma unroll
        for (int r = 0; r < ROWS_A; ++r) { pI[r][m] = accI[r]; pJ[r][m] = accJ[r]; }
    }
    __syncthreads();
    if (!ks) {
#pragma unroll
        for (int r = 0; r < ROWS_A; ++r) {
            hWi[(size_t)(row0 + r) * Mc + m] = accI[r] + pI[r][m];
            hWj[(size_t)(row0 + r) * Mc + m] = accJ[r] + pJ[r][m];
        }
    }
}

// ---------------- Kernel B: fused pairwise core (TI=1, minimal state) ----------------
__global__ __launch_bounds__(256, 4) void egnn_main(
    const float* __restrict__ x,
    const float* __restrict__ Wm, const float* __restrict__ bm,
    const float* __restrict__ Wp, const float* __restrict__ bp,
    const float* __restrict__ hWi, const float* __restrict__ hWj,
    float* __restrict__ xout, float* __restrict__ smw)
{
    const int t = threadIdx.x;
    const int kq = t & 31;        // k-quad index: k = kq*4 + kk
    const int jp = t >> 5;        // j parity 0..7
    const int lane = t & 63;
    const int wv = t >> 6;

    const int b = blockIdx.x >> 9;
    const int i = blockIdx.x & (Nc - 1);

    __shared__ float4 rbuf[Nc];           // 8 KB; diag row = 0; red aliased after loop
    __shared__ float  rs[3];              // sum_j r
    __shared__ float  xred[4][3];
    float (*red)[32][4] = (float(*)[32][4])rbuf;   // [wv][kq<32][kk] = 2 KB

    // build rbuf straight from global x (x[b] = 6KB, L2/L3-hot)
    const float* xg = x + (size_t)b * Nc * 3;
    const float a0 = xg[i * 3 + 0], a1 = xg[i * 3 + 1], a2 = xg[i * 3 + 2];
    for (int n = t; n < Nc; n += 256) {
        const float r0 = xg[n * 3 + 0] - a0;
        const float r1 = xg[n * 3 + 1] - a1;
        const float r2 = xg[n * 3 + 2] - a2;
        rbuf[n] = make_float4(r0, r1, r2, r0*r0 + r1*r1 + r2*r2);
    }
    __syncthreads();

    // rs[c] = sum_j r[j][c] (diag row is 0 so equals masked sum)
    if (wv == 0) {
        float s0 = 0.f, s1 = 0.f, s2 = 0.f;
        for (int j = lane; j < Nc; j += 64) {
            const float4 q = rbuf[j];
            s0 += q.x; s1 += q.y; s2 += q.z;
        }
#pragma unroll
        for (int off = 32; off; off >>= 1) {
            s0 += __shfl_down(s0, off);
            s1 += __shfl_down(s1, off);
            s2 += __shfl_down(s2, off);
        }
        if (lane == 0) { rs[0] = s0; rs[1] = s1; rs[2] = s2; }
    }

    const size_t rowb = (size_t)b * Nc;
    const int k0 = kq * 4;
    const f2 z2 = {0.f, 0.f};

    const float4 bm4 = *(const float4*)(bm + k0);
    const float4 wd4 = *(const float4*)(Wm + (size_t)2 * Hc * Mc + k0);
    const f2 wd2[2] = { {wd4.x, wd4.y}, {wd4.z, wd4.w} };

    f2 cik2[2];
    {
        const float4 c4 = *(const float4*)(hWj + (rowb + i) * Mc + k0);
        cik2[0] = f2{c4.x + bm4.x, c4.y + bm4.y};
        cik2[1] = f2{c4.z + bm4.z, c4.w + bm4.w};
    }

    const float* __restrict__ hWk = hWi + rowb * Mc + k0;

    // sm2 initialized to MINUS the diagonal term (rbuf diag=0 keeps x-path clean)
    f2 sm2[2] = { z2, z2 };
    if ((i & 7) == jp) {
        const float4 hd4 = *(const float4*)(hWk + (size_t)i * Mc);
        sm2[0] = -__builtin_elementwise_max(cik2[0] + f2{hd4.x, hd4.y}, z2);
        sm2[1] = -__builtin_elementwise_max(cik2[1] + f2{hd4.z, hd4.w}, z2);
    }

    f2 af[2][3] = {};                    // [pair][c]

#pragma unroll 2
    for (int it = 0; it < Nc / 8; ++it) {
        const int j = jp + it * 8;
        const float4 hw4 = *(const float4*)(hWk + (size_t)j * Mc);
        const float4 q = rbuf[j];
        const f2 g2[2] = { {hw4.x, hw4.y}, {hw4.z, hw4.w} };
        const f2 d2b = {q.w, q.w}, qxb = {q.x, q.x};
        const f2 qyb = {q.y, q.y}, qzb = {q.z, q.z};
#pragma unroll
        for (int p = 0; p < 2; ++p) {
            const f2 u = __builtin_elementwise_fma(d2b, wd2[p], cik2[p]) + g2[p];
            const f2 mv = __builtin_elementwise_max(u, z2);
            sm2[p] += mv;
            af[p][0] = __builtin_elementwise_fma(mv, qxb, af[p][0]);
            af[p][1] = __builtin_elementwise_fma(mv, qyb, af[p][1]);
            af[p][2] = __builtin_elementwise_fma(mv, qzb, af[p][2]);
        }
    }

    __syncthreads();   // rbuf reads done block-wide; safe to reuse as red

    // ---- sm reduction: combine lane^32 (jp pair) in-register, then LDS ----
#pragma unroll
    for (int p = 0; p < 2; ++p) {
        sm2[p].x += __shfl_xor(sm2[p].x, 32);
        sm2[p].y += __shfl_xor(sm2[p].y, 32);
    }
    if (lane < 32) {
        *(f2*)&red[wv][lane][0] = sm2[0];
        *(f2*)&red[wv][lane][2] = sm2[1];
    }
    __syncthreads();
    if (t < Mc) {
        const int kq2 = t >> 2, kk2 = t & 3;
        smw[(rowb + i) * Mc + t] = red[0][kq2][kk2] + red[1][kq2][kk2]
                                 + red[2][kq2][kk2] + red[3][kq2][kk2];
    }

    // ---- x reduction (Wp loaded only here — epilogue) ----
    const float4* wpv = (const float4*)(Wp + (size_t)k0 * 3);
    const float4 w0 = wpv[0], w1 = wpv[1], w2 = wpv[2];
    const float wpf[12] = { w0.x, w0.y, w0.z, w0.w, w1.x, w1.y, w1.z, w1.w,
                            w2.x, w2.y, w2.z, w2.w };
    float v[3];
#pragma unroll
    for (int c = 0; c < 3; ++c)
        v[c] = af[0][c].x * wpf[0 * 3 + c] + af[0][c].y * wpf[1 * 3 + c]
             + af[1][c].x * wpf[2 * 3 + c] + af[1][c].y * wpf[3 * 3 + c];
#pragma unroll
    for (int off = 32; off; off >>= 1)
#pragma unroll
        for (int c = 0; c < 3; ++c)
            v[c] += __shfl_down(v[c], off);
    if (lane == 0)
#pragma unroll
        for (int c = 0; c < 3; ++c)
            xred[wv][c] = v[c];
    __syncthreads();
    if (t == 0) {
        const float inv = 1.f / (float)(Nc - 1);
#pragma unroll
        for (int c = 0; c < 3; ++c) {
            const float s = xred[0][c] + xred[1][c] + xred[2][c] + xred[3][c]
                          + bp[c] * rs[c];
            xout[(rowb + i) * 3 + c] = xg[i * 3 + c] + s * inv;
        }
    }
}

// ---------------- Kernel C: h_new = [h | sm] @ Wf + bf ----------------
__global__ __launch_bounds__(256) void egnn_hout(
    const float* __restrict__ h, const float* __restrict__ sm,
    const float* __restrict__ Wf, const float* __restrict__ bf,
    float* __restrict__ hout)
{
    __shared__ float hs[ROWS_C][Hc], ss[ROWS_C][Mc];
    __shared__ float part[ROWS_C][Hc];
    const int t = threadIdx.x;
    const int o = t & 127, ks = t >> 7;   // ks0: h-part, ks1: sm-part
    const int row0 = blockIdx.x * ROWS_C;

    for (int idx = t; idx < ROWS_C * Hc; idx += 256) {
        ((float*)hs)[idx] = h[(size_t)row0 * Hc + idx];
        ((float*)ss)[idx] = sm[(size_t)row0 * Mc + idx];
    }
    __syncthreads();

    float acc[ROWS_C] = {};
    const float* src = ks ? &ss[0][0] : &hs[0][0];
    const float* Wb = Wf + (size_t)ks * Hc * Hc;
#pragma unroll 4
    for (int k = 0; k < Hc; ++k) {
        const float w = Wb[(size_t)k * Hc + o];
#pragma unroll
        for (int r = 0; r < ROWS_C; ++r)
            acc[r] = fmaf(src[r * Hc + k], w, acc[r]);
    }
    if (ks) {
#pragma unroll
        for (int r = 0; r < ROWS_C; ++r) part[r][o] = acc[r];
    }
    __syncthreads();
    if (!ks) {
        const float bo = bf[o];
#pragma unroll
        for (int r = 0; r < ROWS_C; ++r)
            hout[(size_t)(row0 + r) * Hc + o] = acc[r] + part[r][o] + bo;
    }
}

extern "C" void kernel_launch(void* const* d_in, const int* in_sizes, int n_in,
                              void* d_out, int out_size, void* d_ws, size_t ws_size,
                              hipStream_t stream)
{
    const float* x  = (const float*)d_in[0];
    const float* h  = (const float*)d_in[1];
    // d_in[2] = mask (all-True; handled structurally)
    const float* Wm = (const float*)d_in[3];
    const float* bm = (const float*)d_in[4];
    const float* Wp = (const float*)d_in[5];
    const float* bp = (const float*)d_in[6];
    const float* Wf = (const float*)d_in[7];
    const float* bf = (const float*)d_in[8];

    float* xout = (float*)d_out;                         // (B,N,3)
    float* hout = (float*)d_out + (size_t)Bc * Nc * 3;   // (B,N,H)

    float* hWi = (float*)d_ws;                            // 1 MB
    float* hWj = hWi + (size_t)Bc * Nc * Mc;              // 1 MB
    float* smw = hWj + (size_t)Bc * Nc * Mc;              // 1 MB

    egnn_proj<<<Bc * Nc / ROWS_A, 256, 0, stream>>>(h, Wm, hWi, hWj);
    egnn_main<<<Bc * Nc, 256, 0, stream>>>(x, Wm, bm, Wp, bp, hWi, hWj, xout, smw);
    egnn_hout<<<Bc * Nc / ROWS_C, 256, 0, stream>>>(h, smw, Wf, bf, hout);
}